// Round 24
// baseline (712.077 us; speedup 1.0000x reference)
//
#include <hip/hip_runtime.h>
#include <hip/hip_bf16.h>
#include <math.h>

typedef __hip_bfloat16 bf16;
typedef __attribute__((ext_vector_type(8))) short short8v;
typedef __attribute__((ext_vector_type(4))) float float4v;

#define B_ 2
#define CIN 96
#define C_ 192
#define N_ 8192
#define NE_ 256
#define TOPK_ 32
#define HEADS_ 8
#define DH_ 24
#define FF_ 768

__device__ __forceinline__ float b2f(bf16 v) { return __bfloat162float(v); }
__device__ __forceinline__ bf16 f2b(float v) { return __float2bfloat16(v); }
__device__ __forceinline__ unsigned short bfb(float v) {
    union { bf16 b; unsigned short u; } t; t.b = __float2bfloat16(v); return t.u;
}
__device__ __forceinline__ float ldx(const float* p, size_t i) { return p[i]; }
__device__ __forceinline__ float ldx(const bf16* p, size_t i) { return __bfloat162float(p[i]); }
__device__ __forceinline__ void stx(float* p, size_t i, float v) { p[i] = v; }
__device__ __forceinline__ void stx(bf16* p, size_t i, float v) { p[i] = __float2bfloat16(v); }
__device__ __forceinline__ float gelu_f(float x) {
    return 0.5f * x * (1.0f + erff(x * 0.7071067811865475f));
}

// ---------- conv as MFMA im2col GEMM; XOR-swizzled LDS + reg prefetch pipeline ----------
__global__ __launch_bounds__(256) void conv_mfma(
    const float* __restrict__ x, const float* __restrict__ cw, const float* __restrict__ cb,
    const float* __restrict__ g, const float* __restrict__ be, const float* __restrict__ mu,
    const float* __restrict__ var, float* __restrict__ xf)
{
    __shared__ unsigned short As[64][64];
    __shared__ unsigned short Bst[64][64];
    int bm = blockIdx.x * 64, bn = blockIdx.y * 64;
    int tid = threadIdx.x;
    int wave = tid >> 6, lane = tid & 63;
    int lrow = lane & 15, lk8 = lane >> 4;
    int r = tid >> 2, kbi = tid & 3;
    int wslot = (kbi ^ (r & 7)) * 8;
    int ng = bm + r;
    int b = ng >> 13, n = ng & 8191;
    int d = n >> 10, h = (n >> 5) & 31, w = n & 31;
    size_t sbase = ((size_t)b * CIN * 16 + 2 * d) * 4096 + (2 * h) * 64 + 2 * w;
    const float* wrow = cw + (size_t)(bn + r) * 768;
    float4v acc[4];
#pragma unroll
    for (int f = 0; f < 4; ++f) acc[f] = (float4v){0.f, 0.f, 0.f, 0.f};
    float2 t0, t1, t2, t3;
    float wreg[8];
    {
        int ci = kbi;
        const float* xb = x + sbase + (size_t)ci * 16 * 4096;
        t0 = *(const float2*)(xb);
        t1 = *(const float2*)(xb + 64);
        t2 = *(const float2*)(xb + 4096);
        t3 = *(const float2*)(xb + 4160);
        const float* wq = wrow + kbi * 8;
#pragma unroll
        for (int j = 0; j < 8; ++j) wreg[j] = wq[j];
    }
    for (int k0 = 0; k0 < 768; k0 += 32) {
        As[r][wslot + 0] = bfb(t0.x); As[r][wslot + 1] = bfb(t0.y);
        As[r][wslot + 2] = bfb(t1.x); As[r][wslot + 3] = bfb(t1.y);
        As[r][wslot + 4] = bfb(t2.x); As[r][wslot + 5] = bfb(t2.y);
        As[r][wslot + 6] = bfb(t3.x); As[r][wslot + 7] = bfb(t3.y);
#pragma unroll
        for (int j = 0; j < 8; ++j) Bst[r][wslot + j] = bfb(wreg[j]);
        __syncthreads();
        if (k0 + 32 < 768) {
            int ci = (k0 + 32 + kbi * 8) >> 3;
            const float* xb = x + sbase + (size_t)ci * 16 * 4096;
            t0 = *(const float2*)(xb);
            t1 = *(const float2*)(xb + 64);
            t2 = *(const float2*)(xb + 4096);
            t3 = *(const float2*)(xb + 4160);
            const float* wq = wrow + k0 + 32 + kbi * 8;
#pragma unroll
            for (int j = 0; j < 8; ++j) wreg[j] = wq[j];
        }
        {
            int arow = wave * 16 + lrow;
            short8v av = *(const short8v*)&As[arow][(lk8 ^ (arow & 7)) * 8];
#pragma unroll
            for (int f = 0; f < 4; ++f) {
                int brow = f * 16 + lrow;
                short8v bv = *(const short8v*)&Bst[brow][(lk8 ^ (brow & 7)) * 8];
                acc[f] = __builtin_amdgcn_mfma_f32_16x16x32_bf16(av, bv, acc[f], 0, 0, 0);
            }
        }
        __syncthreads();
    }
#pragma unroll
    for (int f = 0; f < 4; ++f) {
        int co = bn + f * 16 + lrow;
        float bias = cb[co];
        float scale = g[co] / sqrtf(var[co] + 1e-5f);
        float mean = mu[co];
        float shift = be[co];
#pragma unroll
        for (int rr = 0; rr < 4; ++rr) {
            int m = bm + wave * 16 + lk8 * 4 + rr;
            float v = (acc[f][rr] + bias - mean) * scale + shift;
            xf[(size_t)m * C_ + co] = gelu_f(v);
        }
    }
}

// ---------------- per-row sum of squares ----------------
__global__ __launch_bounds__(256) void row_ss(const float* __restrict__ xf, float* __restrict__ ssb)
{
    int row = blockIdx.x * 4 + (threadIdx.x >> 6);
    int lane = threadIdx.x & 63;
    const float* xr = xf + (size_t)row * C_;
    float x0 = xr[lane], x1 = xr[lane + 64], x2 = xr[lane + 128];
    float s = x0 * x0 + x1 * x1 + x2 * x2;
    for (int off = 32; off; off >>= 1) s += __shfl_xor(s, off, 64);
    if (lane == 0) ssb[row] = s;
}

// -------- dist GEMM --------
__global__ __launch_bounds__(256) void dist_gemm(
    const float* __restrict__ xf, const float* __restrict__ ssb, float* __restrict__ D, int b)
{
    __shared__ float As[16][65];
    __shared__ float Bs[16][64];
    __shared__ int ceb[64];
    int bm = blockIdx.x * 64, bn = blockIdx.y * 64;
    int tid = threadIdx.x;
    int tx = tid & 15, ty = tid >> 4;
    if (tid < 64) ceb[tid] = (int)rintf((float)(bm + tid) * (8191.0f / 255.0f));
    __syncthreads();
    float acc[4][4] = {};
    for (int k0 = 0; k0 < C_; k0 += 16) {
        for (int i = tid; i < 1024; i += 256) {
            int m = i >> 4, kk = i & 15;
            As[kk][m] = xf[(size_t)(b * N_ + ceb[m]) * C_ + k0 + kk];
        }
        for (int i = tid; i < 1024; i += 256) {
            int kk = i & 15, n = i >> 4;
            Bs[kk][n] = xf[(size_t)(b * N_ + bn + n) * C_ + k0 + kk];
        }
        __syncthreads();
        for (int kk = 0; kk < 16; ++kk) {
            float av[4], bvv[4];
#pragma unroll
            for (int i = 0; i < 4; ++i) av[i] = As[kk][ty * 4 + i];
#pragma unroll
            for (int j = 0; j < 4; ++j) bvv[j] = Bs[kk][tx * 4 + j];
#pragma unroll
            for (int i = 0; i < 4; ++i)
#pragma unroll
                for (int j = 0; j < 4; ++j) acc[i][j] += av[i] * bvv[j];
        }
        __syncthreads();
    }
#pragma unroll
    for (int i = 0; i < 4; ++i) {
        int m = bm + ty * 4 + i;
        int ce = ceb[ty * 4 + i];
        int dc = ce >> 10, rc = ce & 1023, hc = rc >> 5, wc = rc & 31;
        float cfs = ssb[b * N_ + ce];
#pragma unroll
        for (int j = 0; j < 4; ++j) {
            int n = bn + tx * 4 + j;
            int dn = n >> 10, rn = n & 1023, hn = rn >> 5, wn = rn & 31;
            float fd = 2.0f * (float)(dc - dn), fh = (float)(hc - hn), fw = (float)(wc - wn);
            float dist = cfs + ssb[b * N_ + n] - 2.0f * acc[i][j] + (fd * fd + fh * fh + fw * fw);
            D[(size_t)m * N_ + n] = dist;
        }
    }
}

// -------- top-32 select: 512 threads; 16-slot stripes; wave butterfly + 8-wave reduce --------
__global__ __launch_bounds__(512) void topk_select(
    const float* __restrict__ D, int* __restrict__ members,
    unsigned long long* __restrict__ nodemask, int b)
{
    __shared__ float dist[N_];
    __shared__ float wv_[8];
    __shared__ int wi_[8];
    __shared__ int winner;
    int e = blockIdx.x;
    int tid = threadIdx.x;
    int wave = tid >> 6, lane = tid & 63;
    const float* row = D + (size_t)e * N_;
    float lmin = 3.4e38f; int lidx = 0x7fffffff;
    for (int i = 0; i < 16; ++i) {
        int n = tid + (i << 9);
        float v = row[n];
        dist[n] = v;
        if (v < lmin) { lmin = v; lidx = n; }
    }
    for (int k = 0; k < TOPK_; ++k) {
        float v = lmin; int ix = lidx;
#pragma unroll
        for (int off = 32; off; off >>= 1) {
            float ov = __shfl_xor(v, off, 64); int oi = __shfl_xor(ix, off, 64);
            if (ov < v || (ov == v && oi < ix)) { v = ov; ix = oi; }
        }
        if (lane == 0) { wv_[wave] = v; wi_[wave] = ix; }
        __syncthreads();
        if (tid == 0) {
            float bv2 = wv_[0]; int bi2 = wi_[0];
#pragma unroll
            for (int wq = 1; wq < 8; ++wq) {
                float ov = wv_[wq]; int oi = wi_[wq];
                if (ov < bv2 || (ov == bv2 && oi < bi2)) { bv2 = ov; bi2 = oi; }
            }
            winner = bi2;
            int wn = ((unsigned)bi2 < N_) ? bi2 : 0;
            members[(b * NE_ + e) * TOPK_ + k] = wn;
            atomicOr(&nodemask[(size_t)(b * N_ + wn) * 4 + (e >> 6)], 1ull << (e & 63));
        }
        __syncthreads();
        int ix2 = winner;
        if ((ix2 & 511) == tid) {
            dist[ix2] = 3.4e38f;
            lmin = 3.4e38f; lidx = 0x7fffffff;
            for (int i = 0; i < 16; ++i) {
                int n = tid + (i << 9);
                float dv = dist[n];
                if (dv < lmin) { lmin = dv; lidx = n; }
            }
        }
    }
}

// ---------------- per-row LN stats ----------------
__global__ __launch_bounds__(256) void ln_stats(const float* __restrict__ xf, float2* __restrict__ stats)
{
    int row = blockIdx.x * 4 + (threadIdx.x >> 6);
    int lane = threadIdx.x & 63;
    const float* xr = xf + (size_t)row * C_;
    float x0 = xr[lane], x1 = xr[lane + 64], x2 = xr[lane + 128];
    float s = x0 + x1 + x2;
    for (int off = 32; off; off >>= 1) s += __shfl_xor(s, off, 64);
    float m = s * (1.0f / 192.0f);
    float d0 = x0 - m, d1 = x1 - m, d2 = x2 - m;
    float s2 = d0 * d0 + d1 * d1 + d2 * d2;
    for (int off = 32; off; off >>= 1) s2 += __shfl_xor(s2, off, 64);
    float inv = 1.0f / sqrtf(s2 * (1.0f / 192.0f) + 1e-5f);
    if (lane == 0) stats[row] = make_float2(m, inv);
}

// ---------- fp32 GEMM for edge k/v projections ----------
__global__ __launch_bounds__(256) void gemm_kv(
    const float* __restrict__ A, const float* __restrict__ wk, const float* __restrict__ wv,
    const float* __restrict__ bk, const float* __restrict__ bvv2,
    float* __restrict__ ke, float* __restrict__ ve, int M)
{
    __shared__ float As[16][65];
    __shared__ float Bs[16][64];
    int bm = blockIdx.x * 64;
    int gn = blockIdx.y * 64;
    int sel = gn >= C_;
    const float* Bw = sel ? wv : wk;
    const float* bias = sel ? bvv2 : bk;
    float* Cc = sel ? ve : ke;
    int bn = sel ? gn - C_ : gn;
    int tid = threadIdx.x;
    int tx = tid & 15, ty = tid >> 4;
    float acc[4][4] = {};
    for (int k0 = 0; k0 < C_; k0 += 16) {
        for (int i = tid; i < 1024; i += 256) {
            int m = i >> 4, kk = i & 15;
            As[kk][m] = A[(size_t)(bm + m) * C_ + k0 + kk];
        }
        for (int i = tid; i < 1024; i += 256) {
            int kk = i >> 6, n = i & 63;
            Bs[kk][n] = Bw[(size_t)(k0 + kk) * C_ + bn + n];
        }
        __syncthreads();
        for (int kk = 0; kk < 16; ++kk) {
            float av[4], bvv[4];
#pragma unroll
            for (int i = 0; i < 4; ++i) av[i] = As[kk][ty * 4 + i];
#pragma unroll
            for (int j = 0; j < 4; ++j) bvv[j] = Bs[kk][tx * 4 + j];
#pragma unroll
            for (int i = 0; i < 4; ++i)
#pragma unroll
                for (int j = 0; j < 4; ++j) acc[i][j] += av[i] * bvv[j];
        }
        __syncthreads();
    }
#pragma unroll
    for (int i = 0; i < 4; ++i) {
#pragma unroll
        for (int j = 0; j < 4; ++j) {
            int m = bm + ty * 4 + i, n = bn + tx * 4 + j;
            Cc[(size_t)m * C_ + n] = acc[i][j] + bias[n];
        }
    }
}

// ---------- MFMA bf16 GEMM: 64x64 tile, 4 waves (proven) ----------
template <int LN, int ACT_GELU, int RESID, typename AT, typename CT>
__global__ __launch_bounds__(256) void gemm_mfma(
    const AT* __restrict__ A, const float2* __restrict__ stats,
    const float* __restrict__ lg, const float* __restrict__ lb,
    const float* __restrict__ Bw, const float* __restrict__ bias,
    CT* __restrict__ Cc, int M, int Nn, int K)
{
    __shared__ unsigned short As[64][40];
    __shared__ unsigned short Bst[64][40];
    int bm = blockIdx.x * 64, bn = blockIdx.y * 64;
    int tid = threadIdx.x;
    int wave = tid >> 6, lane = tid & 63;
    int lrow = lane & 15, lk8 = lane >> 4;
    float4v acc[4];
#pragma unroll
    for (int f = 0; f < 4; ++f) acc[f] = (float4v){0.f, 0.f, 0.f, 0.f};
    for (int k0 = 0; k0 < K; k0 += 32) {
        {
            int r = tid >> 2, kb = (tid & 3) * 8;
            float2 st = LN ? stats[bm + r] : make_float2(0.f, 0.f);
            const AT* arow = A + (size_t)(bm + r) * K + k0 + kb;
#pragma unroll
            for (int j = 0; j < 8; ++j) {
                float a = ldx(arow, j);
                if (LN) a = (a - st.x) * st.y * lg[k0 + kb + j] + lb[k0 + kb + j];
                As[r][kb + j] = bfb(a);
            }
        }
        {
            int k = tid >> 3, nb = (tid & 7) * 8;
            const float* brow = Bw + (size_t)(k0 + k) * Nn + bn + nb;
#pragma unroll
            for (int j = 0; j < 8; ++j) Bst[nb + j][k] = bfb(brow[j]);
        }
        __syncthreads();
        short8v av = *(const short8v*)&As[wave * 16 + lrow][lk8 * 8];
#pragma unroll
        for (int f = 0; f < 4; ++f) {
            short8v bv = *(const short8v*)&Bst[f * 16 + lrow][lk8 * 8];
            acc[f] = __builtin_amdgcn_mfma_f32_16x16x32_bf16(av, bv, acc[f], 0, 0, 0);
        }
        __syncthreads();
    }
#pragma unroll
    for (int f = 0; f < 4; ++f) {
#pragma unroll
        for (int r = 0; r < 4; ++r) {
            int m = bm + wave * 16 + lk8 * 4 + r;
            int n = bn + f * 16 + lrow;
            float v = acc[f][r] + bias[n];
            if (ACT_GELU) v = gelu_f(v);
            size_t idx = (size_t)m * Nn + n;
            if (RESID) v += ldx(Cc, idx);
            stx(Cc, idx, v);
        }
    }
}

// ------ MHA1 fused per (b,e) ------
__global__ __launch_bounds__(256) void mha1_fused(
    const float* __restrict__ xf, const float2* __restrict__ stats,
    const float* __restrict__ lg, const float* __restrict__ lb,
    const int* __restrict__ members, const bf16* __restrict__ kproj,
    const float* __restrict__ w, const float* __restrict__ bias,
    float* __restrict__ he)
{
    __shared__ int mem[TOPK_];
    __shared__ float2 sst[TOPK_];
    __shared__ float xrows[TOPK_][C_];
    __shared__ float kv[TOPK_][C_];
    __shared__ float h0[C_], q[C_], probs[256], wrow[HEADS_ * C_], ar[C_];
    int b = blockIdx.x >> 8, e = blockIdx.x & 255;
    int tid = threadIdx.x;
    if (tid < TOPK_) {
        int mn = members[(b * NE_ + e) * TOPK_ + tid];
        if ((unsigned)mn >= N_) mn = 0;
        mem[tid] = mn;
        sst[tid] = stats[b * N_ + mn];
    }
    __syncthreads();
    for (int i = tid; i < TOPK_ * C_; i += 256) {
        int j = i / C_, c = i - j * C_;
        float v = xf[(size_t)(b * N_ + mem[j]) * C_ + c];
        xrows[j][c] = (v - sst[j].x) * sst[j].y * lg[c] + lb[c];
        kv[j][c] = b2f(kproj[(size_t)(b * N_ + mem[j]) * C_ + c]);
    }
    __syncthreads();
    if (tid < C_) {
        float s = 0.f;
        for (int j = 0; j < TOPK_; ++j) s += xrows[j][tid];
        h0[tid] = s * (1.0f / 32.0f);
    }
    __syncthreads();
    if (tid < C_) {
        float acc = bias[tid];
        for (int k = 0; k < C_; ++k) acc += h0[k] * w[k * C_ + tid];
        q[tid] = acc;
    }
    __syncthreads();
    {
        int hh = tid >> 5, j = tid & 31;
        float s = 0.f;
        for (int d = 0; d < DH_; ++d) s += q[hh * DH_ + d] * kv[j][hh * DH_ + d];
        s *= 0.20412414523193154f;
        float mx = s;
        for (int off = 16; off; off >>= 1) mx = fmaxf(mx, __shfl_xor(mx, off, 32));
        float ex = expf(s - mx);
        float sm = ex;
        for (int off = 16; off; off >>= 1) sm += __shfl_xor(sm, off, 32);
        probs[tid] = ex / sm;
    }
    __syncthreads();
    for (int i = tid; i < HEADS_ * C_; i += 256) {
        int hh = i / C_, k = i - hh * C_;
        const float* pb = probs + hh * 32;
        float acc = 0.f;
        for (int j = 0; j < TOPK_; ++j) acc += pb[j] * xrows[j][k];
        wrow[i] = acc;
    }
    __syncthreads();
    if (tid < C_) {
        int hh = tid / DH_;
        const float* wv2 = w + 2 * C_ * C_;
        const float* wr2 = wrow + hh * C_;
        float acc = bias[2 * C_ + tid];
        for (int k = 0; k < C_; ++k) acc += wr2[k] * wv2[k * C_ + tid];
        ar[tid] = acc;
    }
    __syncthreads();
    if (tid < C_) {
        const float* wo = w + 3 * C_ * C_;
        float acc = bias[3 * C_ + tid];
        for (int k = 0; k < C_; ++k) acc += ar[k] * wo[k * C_ + tid];
        he[(size_t)(b * NE_ + e) * C_ + tid] = acc;
    }
}

// ------- MHA2 attention only -------
__global__ __launch_bounds__(64) void mha2_attn(
    bf16* __restrict__ sbuf, const float* __restrict__ ke, const float* __restrict__ ve,
    const unsigned long long* __restrict__ nodemask)
{
    __shared__ unsigned short lst[NE_];
    __shared__ int cnt;
    __shared__ float qr[C_], sc[HEADS_ * NE_], hsum[HEADS_];
    int blk = blockIdx.x;
    int b = blk >> 13, n = blk & 8191;
    int tid = threadIdx.x;
    size_t row = (size_t)(b * N_ + n) * C_;
    if (tid == 0) {
        int c = 0;
        for (int wd = 0; wd < 4; ++wd) {
            unsigned long long m = nodemask[(size_t)(b * N_ + n) * 4 + wd];
            while (m) {
                int t = __builtin_ctzll(m);
                lst[c++] = (unsigned short)(wd * 64 + t);
                m &= m - 1;
            }
        }
        cnt = c;
    }
    for (int c = tid; c < C_; c += 64) qr[c] = b2f(sbuf[row + c]);
    __syncthreads();
    int m_ = cnt;
    if (m_ == 0) {
        for (int c = tid; c < C_; c += 64) sbuf[row + c] = f2b(0.0f);
        return;
    }
    int hh = tid >> 3, slot = tid & 7;
    float mx = -3.4e38f;
    for (int j = slot; j < m_; j += 8) {
        const float* kr = ke + (size_t)(b * NE_ + lst[j]) * C_ + hh * DH_;
        const float* qh = qr + hh * DH_;
        float s = 0.f;
        for (int d = 0; d < DH_; ++d) s += qh[d] * kr[d];
        s *= 0.20412414523193154f;
        sc[hh * NE_ + j] = s;
        mx = fmaxf(mx, s);
    }
    for (int off = 4; off; off >>= 1) mx = fmaxf(mx, __shfl_xor(mx, off, 8));
    float sum = 0.f;
    for (int j = slot; j < m_; j += 8) {
        float ex = expf(sc[hh * NE_ + j] - mx);
        sc[hh * NE_ + j] = ex;
        sum += ex;
    }
    for (int off = 4; off; off >>= 1) sum += __shfl_xor(sum, off, 8);
    if (slot == 0) hsum[hh] = sum;
    __syncthreads();
    for (int c = tid; c < C_; c += 64) {
        int h2 = c / DH_;
        float acc = 0.f;
        for (int j = 0; j < m_; ++j) acc += sc[h2 * NE_ + j] * ve[(size_t)(b * NE_ + lst[j]) * C_ + c];
        sbuf[row + c] = f2b(acc / hsum[h2]);
    }
}

// ---------------- output: (B,N,C) -> (B,C,N) FP32 ----------------
__global__ __launch_bounds__(256) void write_out_f32(const float* __restrict__ xf, float* __restrict__ out)
{
    __shared__ float t[64 * 193];
    int blk = blockIdx.x;
    int b = blk >> 7, n0 = (blk & 127) * 64;
    for (int i = threadIdx.x; i < 64 * 192; i += 256) {
        int n = i / 192, c = i - (i / 192) * 192;
        t[n * 193 + c] = xf[(size_t)(b * N_ + n0 + n) * C_ + c];
    }
    __syncthreads();
    for (int i = threadIdx.x; i < 64 * 192; i += 256) {
        int c = i >> 6, n = i & 63;
        out[(size_t)(b * C_ + c) * N_ + n0 + n] = t[n * 193 + c];
    }
}

extern "C" void kernel_launch(void* const* d_in, const int* in_sizes, int n_in,
                              void* d_out, int out_size, void* d_ws, size_t ws_size,
                              hipStream_t stream)
{
    const float* x   = (const float*)d_in[0];
    const float* cw  = (const float*)d_in[1];
    const float* cb  = (const float*)d_in[2];
    const float* bg  = (const float*)d_in[3];
    const float* bb  = (const float*)d_in[4];
    const float* bm  = (const float*)d_in[5];
    const float* bv  = (const float*)d_in[6];
    const float* lng = (const float*)d_in[7];
    const float* lnb = (const float*)d_in[8];
    const float* aw  = (const float*)d_in[9];
    const float* ab  = (const float*)d_in[10];
    const float* m1  = (const float*)d_in[11];
    const float* mb1 = (const float*)d_in[12];
    const float* m2  = (const float*)d_in[13];
    const float* mb2 = (const float*)d_in[14];
    float* out = (float*)d_out;

    float* xf = (float*)d_ws;
    char* ob = (char*)d_out;
    float* D = (float*)ob;
    unsigned long long* nodemask = (unsigned long long*)(ob + 8388608);
    int* members = (int*)(ob + 8912896);
    float* ssb   = (float*)(ob + 8978432);
    bf16* sbuf = (bf16*)ob;
    char* ob2 = ob + 6291456;
    float2* stats = (float2*)(ob2 + 524288);
    float* he     = (float*)(ob2 + 720896);
    float* ke     = (float*)(ob2 + 1114112);
    float* ve     = (float*)(ob2 + 1507328);

    hipMemsetAsync(nodemask, 0, (size_t)B_ * N_ * 4 * sizeof(unsigned long long), stream);

    const int MT = B_ * N_;
    {
        dim3 gc(MT / 64, C_ / 64);
        conv_mfma<<<gc, 256, 0, stream>>>(x, cw, cb, bg, bb, bm, bv, xf);
    }
    row_ss<<<MT / 4, 256, 0, stream>>>(xf, ssb);
    for (int b = 0; b < B_; ++b) {
        dim3 gd(4, N_ / 64);
        dist_gemm<<<gd, 256, 0, stream>>>(xf, ssb, D, b);
        topk_select<<<NE_, 512, 0, stream>>>(D, members, nodemask, b);
    }

    for (int i = 0; i < 2; ++i) {
        const float* w0 = aw + (size_t)((i * 2 + 0) * 4) * C_ * C_;
        const float* b0 = ab + (size_t)((i * 2 + 0) * 4) * C_;
        const float* w1 = aw + (size_t)((i * 2 + 1) * 4) * C_ * C_;
        const float* b1 = ab + (size_t)((i * 2 + 1) * 4) * C_;
        const float* g1 = lng + (i * 3 + 0) * C_, *bb1 = lnb + (i * 3 + 0) * C_;
        const float* g2 = lng + (i * 3 + 1) * C_, *bb2 = lnb + (i * 3 + 1) * C_;
        const float* g3 = lng + (i * 3 + 2) * C_, *bb3 = lnb + (i * 3 + 2) * C_;

        ln_stats<<<MT / 4, 256, 0, stream>>>(xf, stats);
        {
            dim3 gk(MT / 64, C_ / 64);
            gemm_mfma<1, 0, 0, float, bf16><<<gk, 256, 0, stream>>>(
                xf, stats, g1, bb1, w0 + 1 * C_ * C_, b0 + 1 * C_, sbuf, MT, C_, C_);
        }
        mha1_fused<<<B_ * NE_, 256, 0, stream>>>(xf, stats, g1, bb1, members, sbuf, w0, b0, he);

        {
            dim3 ge(B_ * NE_ / 64, 6);
            gemm_kv<<<ge, 256, 0, stream>>>(he, w1 + 1 * C_ * C_, w1 + 2 * C_ * C_,
                                            b1 + 1 * C_, b1 + 2 * C_, ke, ve, B_ * NE_);
            dim3 gq(MT / 64, C_ / 64);
            gemm_mfma<1, 0, 0, float, bf16><<<gq, 256, 0, stream>>>(
                xf, stats, g2, bb2, w1 + 0 * C_ * C_, b1 + 0 * C_, sbuf, MT, C_, C_);
        }
        mha2_attn<<<MT, 64, 0, stream>>>(sbuf, ke, ve, nodemask);
        {
            dim3 go(MT / 64, C_ / 64);
            gemm_mfma<0, 0, 1, bf16, float><<<go, 256, 0, stream>>>(
                sbuf, nullptr, nullptr, nullptr, w1 + 3 * C_ * C_, b1 + 3 * C_, xf, MT, C_, C_);
        }

        ln_stats<<<MT / 4, 256, 0, stream>>>(xf, stats);
        for (int ch = 0; ch < 4; ++ch) {
            int off = ch * 4096;
            dim3 g1d(4096 / 64, FF_ / 64);
            gemm_mfma<1, 1, 0, float, bf16><<<g1d, 256, 0, stream>>>(
                xf + (size_t)off * C_, stats + off, g3, bb3,
                m1 + (size_t)i * C_ * FF_, mb1 + i * FF_, sbuf, 4096, FF_, C_);
            dim3 g2d(4096 / 64, C_ / 64);
            gemm_mfma<0, 0, 1, bf16, float><<<g2d, 256, 0, stream>>>(
                sbuf, nullptr, nullptr, nullptr,
                m2 + (size_t)i * FF_ * C_, mb2 + i * C_, xf + (size_t)off * C_, 4096, C_, FF_);
        }
    }
    write_out_f32<<<B_ * N_ / 64, 256, 0, stream>>>(xf, out);
}

// Round 25
// 701.776 us; speedup vs baseline: 1.0147x; 1.0147x over previous
//
#include <hip/hip_runtime.h>
#include <hip/hip_bf16.h>
#include <math.h>

typedef __hip_bfloat16 bf16;
typedef __attribute__((ext_vector_type(8))) short short8v;
typedef __attribute__((ext_vector_type(4))) float float4v;

#define B_ 2
#define CIN 96
#define C_ 192
#define N_ 8192
#define NE_ 256
#define TOPK_ 32
#define HEADS_ 8
#define DH_ 24
#define FF_ 768

__device__ __forceinline__ float b2f(bf16 v) { return __bfloat162float(v); }
__device__ __forceinline__ bf16 f2b(float v) { return __float2bfloat16(v); }
__device__ __forceinline__ unsigned short bfb(float v) {
    union { bf16 b; unsigned short u; } t; t.b = __float2bfloat16(v); return t.u;
}
__device__ __forceinline__ float ldx(const float* p, size_t i) { return p[i]; }
__device__ __forceinline__ float ldx(const bf16* p, size_t i) { return __bfloat162float(p[i]); }
__device__ __forceinline__ void stx(float* p, size_t i, float v) { p[i] = v; }
__device__ __forceinline__ void stx(bf16* p, size_t i, float v) { p[i] = __float2bfloat16(v); }
__device__ __forceinline__ float gelu_f(float x) {
    return 0.5f * x * (1.0f + erff(x * 0.7071067811865475f));
}

// ---------- conv as MFMA im2col GEMM (float2-vectorized gather) ----------
__global__ __launch_bounds__(256) void conv_mfma(
    const float* __restrict__ x, const float* __restrict__ cw, const float* __restrict__ cb,
    const float* __restrict__ g, const float* __restrict__ be, const float* __restrict__ mu,
    const float* __restrict__ var, float* __restrict__ xf)
{
    __shared__ unsigned short As[64][40];
    __shared__ unsigned short Bst[64][40];
    int bm = blockIdx.x * 64, bn = blockIdx.y * 64;
    int tid = threadIdx.x;
    int wave = tid >> 6, lane = tid & 63;
    int lrow = lane & 15, lk8 = lane >> 4;
    int r = tid >> 2, kb = (tid & 3) * 8;
    int ng = bm + r;
    int b = ng >> 13, n = ng & 8191;
    int d = n >> 10, h = (n >> 5) & 31, w = n & 31;
    size_t sbase = ((size_t)b * CIN * 16 + 2 * d) * 4096 + (2 * h) * 64 + 2 * w;
    const float* wrow = cw + (size_t)(bn + r) * 768;
    float4v acc[4];
#pragma unroll
    for (int f = 0; f < 4; ++f) acc[f] = (float4v){0.f, 0.f, 0.f, 0.f};
    for (int k0 = 0; k0 < 768; k0 += 32) {
        {
            int ci = (k0 + kb) >> 3;
            const float* xb = x + sbase + (size_t)ci * 16 * 4096;
            float2 t0 = *(const float2*)(xb);
            float2 t1 = *(const float2*)(xb + 64);
            float2 t2 = *(const float2*)(xb + 4096);
            float2 t3 = *(const float2*)(xb + 4160);
            As[r][kb + 0] = bfb(t0.x); As[r][kb + 1] = bfb(t0.y);
            As[r][kb + 2] = bfb(t1.x); As[r][kb + 3] = bfb(t1.y);
            As[r][kb + 4] = bfb(t2.x); As[r][kb + 5] = bfb(t2.y);
            As[r][kb + 6] = bfb(t3.x); As[r][kb + 7] = bfb(t3.y);
        }
        {
            const float* wq = wrow + k0 + kb;
#pragma unroll
            for (int j = 0; j < 8; ++j) Bst[r][kb + j] = bfb(wq[j]);
        }
        __syncthreads();
        short8v av = *(const short8v*)&As[wave * 16 + lrow][lk8 * 8];
#pragma unroll
        for (int f = 0; f < 4; ++f) {
            short8v bv = *(const short8v*)&Bst[f * 16 + lrow][lk8 * 8];
            acc[f] = __builtin_amdgcn_mfma_f32_16x16x32_bf16(av, bv, acc[f], 0, 0, 0);
        }
        __syncthreads();
    }
#pragma unroll
    for (int f = 0; f < 4; ++f) {
        int co = bn + f * 16 + lrow;
        float bias = cb[co];
        float scale = g[co] / sqrtf(var[co] + 1e-5f);
        float mean = mu[co];
        float shift = be[co];
#pragma unroll
        for (int rr = 0; rr < 4; ++rr) {
            int m = bm + wave * 16 + lk8 * 4 + rr;
            float v = (acc[f][rr] + bias - mean) * scale + shift;
            xf[(size_t)m * C_ + co] = gelu_f(v);
        }
    }
}

// ---------------- per-row sum of squares ----------------
__global__ __launch_bounds__(256) void row_ss(const float* __restrict__ xf, float* __restrict__ ssb)
{
    int row = blockIdx.x * 4 + (threadIdx.x >> 6);
    int lane = threadIdx.x & 63;
    const float* xr = xf + (size_t)row * C_;
    float x0 = xr[lane], x1 = xr[lane + 64], x2 = xr[lane + 128];
    float s = x0 * x0 + x1 * x1 + x2 * x2;
    for (int off = 32; off; off >>= 1) s += __shfl_xor(s, off, 64);
    if (lane == 0) ssb[row] = s;
}

// -------- dist GEMM --------
__global__ __launch_bounds__(256) void dist_gemm(
    const float* __restrict__ xf, const float* __restrict__ ssb, float* __restrict__ D, int b)
{
    __shared__ float As[16][65];
    __shared__ float Bs[16][64];
    __shared__ int ceb[64];
    int bm = blockIdx.x * 64, bn = blockIdx.y * 64;
    int tid = threadIdx.x;
    int tx = tid & 15, ty = tid >> 4;
    if (tid < 64) ceb[tid] = (int)rintf((float)(bm + tid) * (8191.0f / 255.0f));
    __syncthreads();
    float acc[4][4] = {};
    for (int k0 = 0; k0 < C_; k0 += 16) {
        for (int i = tid; i < 1024; i += 256) {
            int m = i >> 4, kk = i & 15;
            As[kk][m] = xf[(size_t)(b * N_ + ceb[m]) * C_ + k0 + kk];
        }
        for (int i = tid; i < 1024; i += 256) {
            int kk = i & 15, n = i >> 4;
            Bs[kk][n] = xf[(size_t)(b * N_ + bn + n) * C_ + k0 + kk];
        }
        __syncthreads();
        for (int kk = 0; kk < 16; ++kk) {
            float av[4], bvv[4];
#pragma unroll
            for (int i = 0; i < 4; ++i) av[i] = As[kk][ty * 4 + i];
#pragma unroll
            for (int j = 0; j < 4; ++j) bvv[j] = Bs[kk][tx * 4 + j];
#pragma unroll
            for (int i = 0; i < 4; ++i)
#pragma unroll
                for (int j = 0; j < 4; ++j) acc[i][j] += av[i] * bvv[j];
        }
        __syncthreads();
    }
#pragma unroll
    for (int i = 0; i < 4; ++i) {
        int m = bm + ty * 4 + i;
        int ce = ceb[ty * 4 + i];
        int dc = ce >> 10, rc = ce & 1023, hc = rc >> 5, wc = rc & 31;
        float cfs = ssb[b * N_ + ce];
#pragma unroll
        for (int j = 0; j < 4; ++j) {
            int n = bn + tx * 4 + j;
            int dn = n >> 10, rn = n & 1023, hn = rn >> 5, wn = rn & 31;
            float fd = 2.0f * (float)(dc - dn), fh = (float)(hc - hn), fw = (float)(wc - wn);
            float dist = cfs + ssb[b * N_ + n] - 2.0f * acc[i][j] + (fd * fd + fh * fh + fw * fw);
            D[(size_t)m * N_ + n] = dist;
        }
    }
}

// -------- top-32 select: 256 threads; wave butterfly + 4-candidate reduce --------
__global__ __launch_bounds__(256) void topk_select(
    const float* __restrict__ D, int* __restrict__ members,
    unsigned long long* __restrict__ nodemask, int b)
{
    __shared__ float dist[N_];
    __shared__ float wv_[4];
    __shared__ int wi_[4];
    __shared__ int winner;
    int e = blockIdx.x;
    int tid = threadIdx.x;
    int wave = tid >> 6, lane = tid & 63;
    const float* row = D + (size_t)e * N_;
    float lmin = 3.4e38f; int lidx = 0x7fffffff;
    for (int i = 0; i < 32; ++i) {
        int n = tid + (i << 8);
        float v = row[n];
        dist[n] = v;
        if (v < lmin) { lmin = v; lidx = n; }
    }
    for (int k = 0; k < TOPK_; ++k) {
        float v = lmin; int ix = lidx;
#pragma unroll
        for (int off = 32; off; off >>= 1) {
            float ov = __shfl_xor(v, off, 64); int oi = __shfl_xor(ix, off, 64);
            if (ov < v || (ov == v && oi < ix)) { v = ov; ix = oi; }
        }
        if (lane == 0) { wv_[wave] = v; wi_[wave] = ix; }
        __syncthreads();
        if (tid == 0) {
            float bv2 = wv_[0]; int bi2 = wi_[0];
#pragma unroll
            for (int wq = 1; wq < 4; ++wq) {
                float ov = wv_[wq]; int oi = wi_[wq];
                if (ov < bv2 || (ov == bv2 && oi < bi2)) { bv2 = ov; bi2 = oi; }
            }
            winner = bi2;
            int wn = ((unsigned)bi2 < N_) ? bi2 : 0;
            members[(b * NE_ + e) * TOPK_ + k] = wn;
            atomicOr(&nodemask[(size_t)(b * N_ + wn) * 4 + (e >> 6)], 1ull << (e & 63));
        }
        __syncthreads();
        int ix2 = winner;
        if ((ix2 & 255) == tid) {
            dist[ix2] = 3.4e38f;
            lmin = 3.4e38f; lidx = 0x7fffffff;
            for (int i = 0; i < 32; ++i) {
                int n = tid + (i << 8);
                float dv = dist[n];
                if (dv < lmin) { lmin = dv; lidx = n; }
            }
        }
    }
}

// ---------------- per-row LN stats ----------------
__global__ __launch_bounds__(256) void ln_stats(const float* __restrict__ xf, float2* __restrict__ stats)
{
    int row = blockIdx.x * 4 + (threadIdx.x >> 6);
    int lane = threadIdx.x & 63;
    const float* xr = xf + (size_t)row * C_;
    float x0 = xr[lane], x1 = xr[lane + 64], x2 = xr[lane + 128];
    float s = x0 + x1 + x2;
    for (int off = 32; off; off >>= 1) s += __shfl_xor(s, off, 64);
    float m = s * (1.0f / 192.0f);
    float d0 = x0 - m, d1 = x1 - m, d2 = x2 - m;
    float s2 = d0 * d0 + d1 * d1 + d2 * d2;
    for (int off = 32; off; off >>= 1) s2 += __shfl_xor(s2, off, 64);
    float inv = 1.0f / sqrtf(s2 * (1.0f / 192.0f) + 1e-5f);
    if (lane == 0) stats[row] = make_float2(m, inv);
}

// ---------- fp32 GEMM for edge k/v projections ----------
__global__ __launch_bounds__(256) void gemm_kv(
    const float* __restrict__ A, const float* __restrict__ wk, const float* __restrict__ wv,
    const float* __restrict__ bk, const float* __restrict__ bvv2,
    float* __restrict__ ke, float* __restrict__ ve, int M)
{
    __shared__ float As[16][65];
    __shared__ float Bs[16][64];
    int bm = blockIdx.x * 64;
    int gn = blockIdx.y * 64;
    int sel = gn >= C_;
    const float* Bw = sel ? wv : wk;
    const float* bias = sel ? bvv2 : bk;
    float* Cc = sel ? ve : ke;
    int bn = sel ? gn - C_ : gn;
    int tid = threadIdx.x;
    int tx = tid & 15, ty = tid >> 4;
    float acc[4][4] = {};
    for (int k0 = 0; k0 < C_; k0 += 16) {
        for (int i = tid; i < 1024; i += 256) {
            int m = i >> 4, kk = i & 15;
            As[kk][m] = A[(size_t)(bm + m) * C_ + k0 + kk];
        }
        for (int i = tid; i < 1024; i += 256) {
            int kk = i >> 6, n = i & 63;
            Bs[kk][n] = Bw[(size_t)(k0 + kk) * C_ + bn + n];
        }
        __syncthreads();
        for (int kk = 0; kk < 16; ++kk) {
            float av[4], bvv[4];
#pragma unroll
            for (int i = 0; i < 4; ++i) av[i] = As[kk][ty * 4 + i];
#pragma unroll
            for (int j = 0; j < 4; ++j) bvv[j] = Bs[kk][tx * 4 + j];
#pragma unroll
            for (int i = 0; i < 4; ++i)
#pragma unroll
                for (int j = 0; j < 4; ++j) acc[i][j] += av[i] * bvv[j];
        }
        __syncthreads();
    }
#pragma unroll
    for (int i = 0; i < 4; ++i) {
#pragma unroll
        for (int j = 0; j < 4; ++j) {
            int m = bm + ty * 4 + i, n = bn + tx * 4 + j;
            Cc[(size_t)m * C_ + n] = acc[i][j] + bias[n];
        }
    }
}

// ---------- MFMA bf16 GEMM: 64x64 tile, 4 waves ----------
template <int LN, int ACT_GELU, int RESID, typename AT, typename CT>
__global__ __launch_bounds__(256) void gemm_mfma(
    const AT* __restrict__ A, const float2* __restrict__ stats,
    const float* __restrict__ lg, const float* __restrict__ lb,
    const float* __restrict__ Bw, const float* __restrict__ bias,
    CT* __restrict__ Cc, int M, int Nn, int K)
{
    __shared__ unsigned short As[64][40];
    __shared__ unsigned short Bst[64][40];
    int bm = blockIdx.x * 64, bn = blockIdx.y * 64;
    int tid = threadIdx.x;
    int wave = tid >> 6, lane = tid & 63;
    int lrow = lane & 15, lk8 = lane >> 4;
    float4v acc[4];
#pragma unroll
    for (int f = 0; f < 4; ++f) acc[f] = (float4v){0.f, 0.f, 0.f, 0.f};
    for (int k0 = 0; k0 < K; k0 += 32) {
        {
            int r = tid >> 2, kb = (tid & 3) * 8;
            float2 st = LN ? stats[bm + r] : make_float2(0.f, 0.f);
            const AT* arow = A + (size_t)(bm + r) * K + k0 + kb;
#pragma unroll
            for (int j = 0; j < 8; ++j) {
                float a = ldx(arow, j);
                if (LN) a = (a - st.x) * st.y * lg[k0 + kb + j] + lb[k0 + kb + j];
                As[r][kb + j] = bfb(a);
            }
        }
        {
            int k = tid >> 3, nb = (tid & 7) * 8;
            const float* brow = Bw + (size_t)(k0 + k) * Nn + bn + nb;
#pragma unroll
            for (int j = 0; j < 8; ++j) Bst[nb + j][k] = bfb(brow[j]);
        }
        __syncthreads();
        short8v av = *(const short8v*)&As[wave * 16 + lrow][lk8 * 8];
#pragma unroll
        for (int f = 0; f < 4; ++f) {
            short8v bv = *(const short8v*)&Bst[f * 16 + lrow][lk8 * 8];
            acc[f] = __builtin_amdgcn_mfma_f32_16x16x32_bf16(av, bv, acc[f], 0, 0, 0);
        }
        __syncthreads();
    }
#pragma unroll
    for (int f = 0; f < 4; ++f) {
#pragma unroll
        for (int r = 0; r < 4; ++r) {
            int m = bm + wave * 16 + lk8 * 4 + r;
            int n = bn + f * 16 + lrow;
            float v = acc[f][r] + bias[n];
            if (ACT_GELU) v = gelu_f(v);
            size_t idx = (size_t)m * Nn + n;
            if (RESID) v += ldx(Cc, idx);
            stx(Cc, idx, v);
        }
    }
}

// ------ MHA1 fused per (b,e) ------
__global__ __launch_bounds__(256) void mha1_fused(
    const float* __restrict__ xf, const float2* __restrict__ stats,
    const float* __restrict__ lg, const float* __restrict__ lb,
    const int* __restrict__ members, const bf16* __restrict__ kproj,
    const float* __restrict__ w, const float* __restrict__ bias,
    float* __restrict__ he)
{
    __shared__ int mem[TOPK_];
    __shared__ float2 sst[TOPK_];
    __shared__ float xrows[TOPK_][C_];
    __shared__ float kv[TOPK_][C_];
    __shared__ float h0[C_], q[C_], probs[256], wrow[HEADS_ * C_], ar[C_];
    int b = blockIdx.x >> 8, e = blockIdx.x & 255;
    int tid = threadIdx.x;
    if (tid < TOPK_) {
        int mn = members[(b * NE_ + e) * TOPK_ + tid];
        if ((unsigned)mn >= N_) mn = 0;
        mem[tid] = mn;
        sst[tid] = stats[b * N_ + mn];
    }
    __syncthreads();
    for (int i = tid; i < TOPK_ * C_; i += 256) {
        int j = i / C_, c = i - j * C_;
        float v = xf[(size_t)(b * N_ + mem[j]) * C_ + c];
        xrows[j][c] = (v - sst[j].x) * sst[j].y * lg[c] + lb[c];
        kv[j][c] = b2f(kproj[(size_t)(b * N_ + mem[j]) * C_ + c]);
    }
    __syncthreads();
    if (tid < C_) {
        float s = 0.f;
        for (int j = 0; j < TOPK_; ++j) s += xrows[j][tid];
        h0[tid] = s * (1.0f / 32.0f);
    }
    __syncthreads();
    if (tid < C_) {
        float acc = bias[tid];
        for (int k = 0; k < C_; ++k) acc += h0[k] * w[k * C_ + tid];
        q[tid] = acc;
    }
    __syncthreads();
    {
        int hh = tid >> 5, j = tid & 31;
        float s = 0.f;
        for (int d = 0; d < DH_; ++d) s += q[hh * DH_ + d] * kv[j][hh * DH_ + d];
        s *= 0.20412414523193154f;
        float mx = s;
        for (int off = 16; off; off >>= 1) mx = fmaxf(mx, __shfl_xor(mx, off, 32));
        float ex = expf(s - mx);
        float sm = ex;
        for (int off = 16; off; off >>= 1) sm += __shfl_xor(sm, off, 32);
        probs[tid] = ex / sm;
    }
    __syncthreads();
    for (int i = tid; i < HEADS_ * C_; i += 256) {
        int hh = i / C_, k = i - hh * C_;
        const float* pb = probs + hh * 32;
        float acc = 0.f;
        for (int j = 0; j < TOPK_; ++j) acc += pb[j] * xrows[j][k];
        wrow[i] = acc;
    }
    __syncthreads();
    if (tid < C_) {
        int hh = tid / DH_;
        const float* wv2 = w + 2 * C_ * C_;
        const float* wr2 = wrow + hh * C_;
        float acc = bias[2 * C_ + tid];
        for (int k = 0; k < C_; ++k) acc += wr2[k] * wv2[k * C_ + tid];
        ar[tid] = acc;
    }
    __syncthreads();
    if (tid < C_) {
        const float* wo = w + 3 * C_ * C_;
        float acc = bias[3 * C_ + tid];
        for (int k = 0; k < C_; ++k) acc += ar[k] * wo[k * C_ + tid];
        he[(size_t)(b * NE_ + e) * C_ + tid] = acc;
    }
}

// ------- MHA2 attention only -------
__global__ __launch_bounds__(64) void mha2_attn(
    bf16* __restrict__ sbuf, const float* __restrict__ ke, const float* __restrict__ ve,
    const unsigned long long* __restrict__ nodemask)
{
    __shared__ unsigned short lst[NE_];
    __shared__ int cnt;
    __shared__ float qr[C_], sc[HEADS_ * NE_], hsum[HEADS_];
    int blk = blockIdx.x;
    int b = blk >> 13, n = blk & 8191;
    int tid = threadIdx.x;
    size_t row = (size_t)(b * N_ + n) * C_;
    if (tid == 0) {
        int c = 0;
        for (int wd = 0; wd < 4; ++wd) {
            unsigned long long m = nodemask[(size_t)(b * N_ + n) * 4 + wd];
            while (m) {
                int t = __builtin_ctzll(m);
                lst[c++] = (unsigned short)(wd * 64 + t);
                m &= m - 1;
            }
        }
        cnt = c;
    }
    for (int c = tid; c < C_; c += 64) qr[c] = b2f(sbuf[row + c]);
    __syncthreads();
    int m_ = cnt;
    if (m_ == 0) {
        for (int c = tid; c < C_; c += 64) sbuf[row + c] = f2b(0.0f);
        return;
    }
    int hh = tid >> 3, slot = tid & 7;
    float mx = -3.4e38f;
    for (int j = slot; j < m_; j += 8) {
        const float* kr = ke + (size_t)(b * NE_ + lst[j]) * C_ + hh * DH_;
        const float* qh = qr + hh * DH_;
        float s = 0.f;
        for (int d = 0; d < DH_; ++d) s += qh[d] * kr[d];
        s *= 0.20412414523193154f;
        sc[hh * NE_ + j] = s;
        mx = fmaxf(mx, s);
    }
    for (int off = 4; off; off >>= 1) mx = fmaxf(mx, __shfl_xor(mx, off, 8));
    float sum = 0.f;
    for (int j = slot; j < m_; j += 8) {
        float ex = expf(sc[hh * NE_ + j] - mx);
        sc[hh * NE_ + j] = ex;
        sum += ex;
    }
    for (int off = 4; off; off >>= 1) sum += __shfl_xor(sum, off, 8);
    if (slot == 0) hsum[hh] = sum;
    __syncthreads();
    for (int c = tid; c < C_; c += 64) {
        int h2 = c / DH_;
        float acc = 0.f;
        for (int j = 0; j < m_; ++j) acc += sc[h2 * NE_ + j] * ve[(size_t)(b * NE_ + lst[j]) * C_ + c];
        sbuf[row + c] = f2b(acc / hsum[h2]);
    }
}

// ---------------- output: (B,N,C) -> (B,C,N) FP32 ----------------
__global__ __launch_bounds__(256) void write_out_f32(const float* __restrict__ xf, float* __restrict__ out)
{
    __shared__ float t[64 * 193];
    int blk = blockIdx.x;
    int b = blk >> 7, n0 = (blk & 127) * 64;
    for (int i = threadIdx.x; i < 64 * 192; i += 256) {
        int n = i / 192, c = i - (i / 192) * 192;
        t[n * 193 + c] = xf[(size_t)(b * N_ + n0 + n) * C_ + c];
    }
    __syncthreads();
    for (int i = threadIdx.x; i < 64 * 192; i += 256) {
        int c = i >> 6, n = i & 63;
        out[(size_t)(b * C_ + c) * N_ + n0 + n] = t[n * 193 + c];
    }
}

extern "C" void kernel_launch(void* const* d_in, const int* in_sizes, int n_in,
                              void* d_out, int out_size, void* d_ws, size_t ws_size,
                              hipStream_t stream)
{
    const float* x   = (const float*)d_in[0];
    const float* cw  = (const float*)d_in[1];
    const float* cb  = (const float*)d_in[2];
    const float* bg  = (const float*)d_in[3];
    const float* bb  = (const float*)d_in[4];
    const float* bm  = (const float*)d_in[5];
    const float* bv  = (const float*)d_in[6];
    const float* lng = (const float*)d_in[7];
    const float* lnb = (const float*)d_in[8];
    const float* aw  = (const float*)d_in[9];
    const float* ab  = (const float*)d_in[10];
    const float* m1  = (const float*)d_in[11];
    const float* mb1 = (const float*)d_in[12];
    const float* m2  = (const float*)d_in[13];
    const float* mb2 = (const float*)d_in[14];
    float* out = (float*)d_out;

    float* xf = (float*)d_ws;
    char* ob = (char*)d_out;
    float* D = (float*)ob;
    unsigned long long* nodemask = (unsigned long long*)(ob + 8388608);
    int* members = (int*)(ob + 8912896);
    float* ssb   = (float*)(ob + 8978432);
    bf16* sbuf = (bf16*)ob;
    char* ob2 = ob + 6291456;
    float2* stats = (float2*)(ob2 + 524288);
    float* he     = (float*)(ob2 + 720896);
    float* ke     = (float*)(ob2 + 1114112);
    float* ve     = (float*)(ob2 + 1507328);

    hipMemsetAsync(nodemask, 0, (size_t)B_ * N_ * 4 * sizeof(unsigned long long), stream);

    const int MT = B_ * N_;
    {
        dim3 gc(MT / 64, C_ / 64);
        conv_mfma<<<gc, 256, 0, stream>>>(x, cw, cb, bg, bb, bm, bv, xf);
    }
    row_ss<<<MT / 4, 256, 0, stream>>>(xf, ssb);
    for (int b = 0; b < B_; ++b) {
        dim3 gd(4, N_ / 64);
        dist_gemm<<<gd, 256, 0, stream>>>(xf, ssb, D, b);
        topk_select<<<NE_, 256, 0, stream>>>(D, members, nodemask, b);
    }

    for (int i = 0; i < 2; ++i) {
        const float* w0 = aw + (size_t)((i * 2 + 0) * 4) * C_ * C_;
        const float* b0 = ab + (size_t)((i * 2 + 0) * 4) * C_;
        const float* w1 = aw + (size_t)((i * 2 + 1) * 4) * C_ * C_;
        const float* b1 = ab + (size_t)((i * 2 + 1) * 4) * C_;
        const float* g1 = lng + (i * 3 + 0) * C_, *bb1 = lnb + (i * 3 + 0) * C_;
        const float* g2 = lng + (i * 3 + 1) * C_, *bb2 = lnb + (i * 3 + 1) * C_;
        const float* g3 = lng + (i * 3 + 2) * C_, *bb3 = lnb + (i * 3 + 2) * C_;

        ln_stats<<<MT / 4, 256, 0, stream>>>(xf, stats);
        {
            dim3 gk(MT / 64, C_ / 64);
            gemm_mfma<1, 0, 0, float, bf16><<<gk, 256, 0, stream>>>(
                xf, stats, g1, bb1, w0 + 1 * C_ * C_, b0 + 1 * C_, sbuf, MT, C_, C_);
        }
        mha1_fused<<<B_ * NE_, 256, 0, stream>>>(xf, stats, g1, bb1, members, sbuf, w0, b0, he);

        {
            dim3 ge(B_ * NE_ / 64, 6);
            gemm_kv<<<ge, 256, 0, stream>>>(he, w1 + 1 * C_ * C_, w1 + 2 * C_ * C_,
                                            b1 + 1 * C_, b1 + 2 * C_, ke, ve, B_ * NE_);
            dim3 gq(MT / 64, C_ / 64);
            gemm_mfma<1, 0, 0, float, bf16><<<gq, 256, 0, stream>>>(
                xf, stats, g2, bb2, w1 + 0 * C_ * C_, b1 + 0 * C_, sbuf, MT, C_, C_);
        }
        mha2_attn<<<MT, 64, 0, stream>>>(sbuf, ke, ve, nodemask);
        {
            dim3 go(MT / 64, C_ / 64);
            gemm_mfma<0, 0, 1, bf16, float><<<go, 256, 0, stream>>>(
                sbuf, nullptr, nullptr, nullptr, w1 + 3 * C_ * C_, b1 + 3 * C_, xf, MT, C_, C_);
        }

        ln_stats<<<MT / 4, 256, 0, stream>>>(xf, stats);
        for (int ch = 0; ch < 4; ++ch) {
            int off = ch * 4096;
            dim3 g1d(4096 / 64, FF_ / 64);
            gemm_mfma<1, 1, 0, float, bf16><<<g1d, 256, 0, stream>>>(
                xf + (size_t)off * C_, stats + off, g3, bb3,
                m1 + (size_t)i * C_ * FF_, mb1 + i * FF_, sbuf, 4096, FF_, C_);
            dim3 g2d(4096 / 64, C_ / 64);
            gemm_mfma<0, 0, 1, bf16, float><<<g2d, 256, 0, stream>>>(
                sbuf, nullptr, nullptr, nullptr,
                m2 + (size_t)i * FF_ * C_, mb2 + i * C_, xf + (size_t)off * C_, 4096, C_, FF_);
        }
    }
    write_out_f32<<<B_ * N_ / 64, 256, 0, stream>>>(xf, out);
}